// Round 18
// baseline (105.276 us; speedup 1.0000x reference)
//
#include <hip/hip_runtime.h>

#define N_POINTS 500000
#define K_CENT   512
#define W_DIM    64
#define N_JOBS   ((N_POINTS + 63) / 64)   // 7813: 64 points per wave-job

typedef _Float16 half8 __attribute__((ext_vector_type(8)));
typedef float    f32x4 __attribute__((ext_vector_type(4)));

// ---- pre-kernel 1: codebook -> 16x16x32-fragment-ordered f16 hi/lo of w=-2c.
// Layout: [t:16][plane:2][csub:2][kstep:2][lane:64][j:8] -> 8 KB/chunk,
// chunk t contiguous (LDS DMA). cent c = t*32 + csub*16 + (l&15),
// dim d = kstep*32 + (l>>4)*8 + j. lo = unscaled residual. (Verified R11-R16.)
__global__ void cvt_kernel(const float* __restrict__ cb,
                           _Float16* __restrict__ cbf) {
    int id = blockIdx.x * 256 + threadIdx.x;           // 4096 ids
    if (id >= K_CENT * 8) return;
    int c = id >> 3, o = (id & 7) * 8;                 // centroid, dim base
    int t = c >> 5, csub = (c >> 4) & 1, r = c & 15;
    int kstep = o >> 5, grp = (o >> 3) & 3;
    int lane = grp * 16 + r;
    const float* src = cb + (size_t)c * W_DIM + o;
    half8 h, l;
#pragma unroll
    for (int j = 0; j < 8; ++j) {
        float w = -2.0f * src[j];
        _Float16 hh = (_Float16)w;                     // RNE
        h[j] = hh;
        l[j] = (_Float16)(w - (float)hh);              // unscaled residual
    }
    size_t bh = ((((size_t)t * 2 + 0) * 2 + csub) * 2 + kstep) * 512 + (size_t)lane * 8;
    size_t bl = ((((size_t)t * 2 + 1) * 2 + csub) * 2 + kstep) * 512 + (size_t)lane * 8;
    *(half8*)(cbf + bh) = h;
    *(half8*)(cbf + bl) = l;
}

// ---- pre-kernel 2: c2[c] = ||c||^2 in double (deterministic)
__global__ void c2_kernel(const float* __restrict__ cb, float* __restrict__ c2) {
    int c = blockIdx.x * 256 + threadIdx.x;
    if (c >= K_CENT) return;
    const float4* row = (const float4*)(cb + (size_t)c * W_DIM);
    double s = 0.0;
#pragma unroll
    for (int j = 0; j < W_DIM / 4; ++j) {
        float4 v = row[j];
        s += (double)v.x * v.x + (double)v.y * v.y + (double)v.z * v.z + (double)v.w * v.w;
    }
    c2[c] = (float)s;
}

#define MFMA16(A, B, C) __builtin_amdgcn_mfma_f32_16x16x32_f16(A, B, C, 0, 0, 0)

// Stage chunk T's 2 KB wave-slice into abuf[BUF] (LDS dest linear, G src per-lane).
#define STAGE(T, BUF)                                                          \
    {                                                                          \
        const __attribute__((address_space(1))) _Float16* g =                  \
            (const __attribute__((address_space(1))) _Float16*)                \
            (cbf + (size_t)(T) * 4096 + (size_t)wave * 1024 + (size_t)lane * 8); \
        __builtin_amdgcn_global_load_lds(                                      \
            (const __attribute__((address_space(1))) void*)g,                  \
            (__attribute__((address_space(3))) void*)&abuf[BUF][wave * 1024],  \
            16, 0, 0);                                                         \
        __builtin_amdgcn_global_load_lds(                                      \
            (const __attribute__((address_space(1))) void*)(g + 512),          \
            (__attribute__((address_space(3))) void*)&abuf[BUF][wave * 1024 + 512], \
            16, 0, 0);                                                         \
    }

// Compute chunk T_ from abuf[BUF] (STATIC index): 48 MFMAs = 8 independent
// chains (cs,ps) x 6-deep, grouped by step (same-chain spacing 8 slots).
// C-in = c2 via q; immediate 8-value argmin per ps with explicit
// (m==bd && ci<bi) tie-break (order-independent under rotation).
#define CHUNK_COMPUTE(BUF, T_)                                                 \
    {                                                                          \
        half8 aH[2][2], aL[2][2];                                              \
        _Pragma("unroll")                                                      \
        for (int cs = 0; cs < 2; ++cs)                                         \
            _Pragma("unroll")                                                  \
            for (int ks = 0; ks < 2; ++ks) {                                   \
                aH[cs][ks] = *(const half8*)&abuf[BUF][(cs * 2 + ks) * 512 + lane * 8]; \
                aL[cs][ks] = *(const half8*)&abuf[BUF][(4 + cs * 2 + ks) * 512 + lane * 8]; \
            }                                                                  \
        f32x4 q0 = *(const f32x4*)&c2s[(T_) * 32 + grp4];                      \
        f32x4 q1 = *(const f32x4*)&c2s[(T_) * 32 + 16 + grp4];                 \
        f32x4 acc[2][4];                                                       \
        __builtin_amdgcn_s_setprio(1);                                         \
        _Pragma("unroll")                                                      \
        for (int cs = 0; cs < 2; ++cs)                                         \
            _Pragma("unroll")                                                  \
            for (int ps = 0; ps < 4; ++ps)                                     \
                acc[cs][ps] = MFMA16(aH[cs][0], bh[ps][0], cs ? q1 : q0);      \
        _Pragma("unroll")                                                      \
        for (int cs = 0; cs < 2; ++cs)                                         \
            _Pragma("unroll")                                                  \
            for (int ps = 0; ps < 4; ++ps)                                     \
                acc[cs][ps] = MFMA16(aH[cs][1], bh[ps][1], acc[cs][ps]);       \
        _Pragma("unroll")                                                      \
        for (int cs = 0; cs < 2; ++cs)                                         \
            _Pragma("unroll")                                                  \
            for (int ps = 0; ps < 4; ++ps)                                     \
                acc[cs][ps] = MFMA16(aL[cs][0], bh[ps][0], acc[cs][ps]);       \
        _Pragma("unroll")                                                      \
        for (int cs = 0; cs < 2; ++cs)                                         \
            _Pragma("unroll")                                                  \
            for (int ps = 0; ps < 4; ++ps)                                     \
                acc[cs][ps] = MFMA16(aL[cs][1], bh[ps][1], acc[cs][ps]);       \
        _Pragma("unroll")                                                      \
        for (int cs = 0; cs < 2; ++cs)                                         \
            _Pragma("unroll")                                                  \
            for (int ps = 0; ps < 4; ++ps)                                     \
                acc[cs][ps] = MFMA16(aH[cs][0], bl[ps][0], acc[cs][ps]);       \
        _Pragma("unroll")                                                      \
        for (int cs = 0; cs < 2; ++cs)                                         \
            _Pragma("unroll")                                                  \
            for (int ps = 0; ps < 4; ++ps)                                     \
                acc[cs][ps] = MFMA16(aH[cs][1], bl[ps][1], acc[cs][ps]);       \
        __builtin_amdgcn_s_setprio(0);                                         \
        _Pragma("unroll")                                                      \
        for (int ps = 0; ps < 4; ++ps) {                                       \
            float v0 = acc[0][ps][0], v1 = acc[0][ps][1];                      \
            float v2 = acc[0][ps][2], v3 = acc[0][ps][3];                      \
            float v4 = acc[1][ps][0], v5 = acc[1][ps][1];                      \
            float v6 = acc[1][ps][2], v7 = acc[1][ps][3];                      \
            float a0 = fminf(v0, v1), a1 = fminf(v2, v3);                      \
            float a2 = fminf(v4, v5), a3 = fminf(v6, v7);                      \
            float b0 = fminf(a0, a1), b1 = fminf(a2, a3);                      \
            float m  = fminf(b0, b1);                                          \
            bool  L2 = (m == b0);                                              \
            float aLv = L2 ? a0 : a2;                                          \
            bool  L1 = (m == aLv);                                             \
            float vE = L2 ? (L1 ? v0 : v2) : (L1 ? v4 : v6);                   \
            bool  L0 = (m == vE);                                              \
            int ji = (L2 ? 0 : 4) | (L1 ? 0 : 2) | (L0 ? 0 : 1);               \
            int ci = (T_) * 32 + (ji >> 2) * 16 + grp4 + (ji & 3);             \
            bool imp = (m < bd[ps]) || (m == bd[ps] && ci < bi[ps]);           \
            bd[ps] = imp ? m : bd[ps];                                         \
            bi[ps] = imp ? ci : bi[ps];                                        \
        }                                                                      \
    }

// ---- main kernel: 4 waves/block, 64 points/wave (4 subtiles of 16), A in
// LDS (block-shared dbuf). Halved jobs -> halved per-point ds_read traffic
// (the R16 binder: A-delivery ~39us/CU now ~19.5us, MFMA 47us dominant).
__global__ __launch_bounds__(256, 2)
void kmeans_mfma(const float* __restrict__ X,
                 const _Float16* __restrict__ cbf,
                 const float* __restrict__ c2,
                 float* __restrict__ out_idx,
                 float* __restrict__ out_dist) {
    __shared__ _Float16 abuf[2][4096];     // 2 x 8 KB A-chunk double buffer
    __shared__ float c2s[K_CENT];          // 2 KB
    int tid = threadIdx.x;
    c2s[tid] = c2[tid];
    c2s[tid + 256] = c2[tid + 256];

    int wave = tid >> 6;
    int lane = tid & 63;
    int l15  = lane & 15;
    int grp  = lane >> 4;        // 0..3
    int grp4 = grp * 4;
    int grp8 = grp * 8;
    int rot  = (blockIdx.x & 7) * 2;   // even rotation: pairs never wrap

    int job   = blockIdx.x * 4 + wave;
    int valid = job < N_JOBS;
    int jc    = valid ? job : (N_JOBS - 1);   // invalid waves still hit barriers

    // ---- load + convert X: 4 point-subtiles x 2 K-steps, 8 dims/lane each
    half8 bh[4][2], bl[4][2];
    float x2[4] = {0.f, 0.f, 0.f, 0.f};
#pragma unroll
    for (int ps = 0; ps < 4; ++ps) {
        int p  = jc * 64 + ps * 16 + l15;
        int pe = p < N_POINTS ? p : (N_POINTS - 1);
#pragma unroll
        for (int ks = 0; ks < 2; ++ks) {
            const float4* xp = (const float4*)(X + (size_t)pe * W_DIM + ks * 32 + grp8);
            float4 f0 = xp[0], f1 = xp[1];
            float fa[8] = {f0.x, f0.y, f0.z, f0.w, f1.x, f1.y, f1.z, f1.w};
#pragma unroll
            for (int j = 0; j < 8; ++j) {
                _Float16 hh = (_Float16)fa[j];
                bh[ps][ks][j] = hh;
                bl[ps][ks][j] = (_Float16)(fa[j] - (float)hh);
                x2[ps] = fmaf(fa[j], fa[j], x2[ps]);
            }
        }
    }
#pragma unroll
    for (int ps = 0; ps < 4; ++ps) {    // full ||x||^2 across the 4 row-groups
        x2[ps] += __shfl_xor(x2[ps], 16);
        x2[ps] += __shfl_xor(x2[ps], 32);
    }

    float bd[4] = {3.4e38f, 3.4e38f, 3.4e38f, 3.4e38f};
    int   bi[4] = {0, 0, 0, 0};

    STAGE(rot, 0)
    __syncthreads();    // drains vmcnt -> abuf[0] + c2s ready

#pragma unroll 1
    for (int it = 0; it < 8; ++it) {
        int ta = (rot + 2 * it) & 15;   // even; pair (ta, ta+1), no wrap
        // phase A: stage pair's 2nd chunk into buf1, compute chunk ta from buf0
        STAGE(ta + 1, 1)
        CHUNK_COMPUTE(0, ta)
        __syncthreads();   // buf1 staged everywhere; all waves done with buf0
        // phase B: stage next pair's 1st chunk into buf0, compute ta+1 from buf1
        if (it < 7) {
            int tn = (ta + 2) & 15;
            STAGE(tn, 0)
        }
        CHUNK_COMPUTE(1, ta + 1)
        __syncthreads();   // buf0 staged everywhere; all waves done with buf1
    }

    // cross-lane combine over the 4 row-groups (disjoint cents per group);
    // explicit lower-index preference on fp-equal ties.
#pragma unroll
    for (int ps = 0; ps < 4; ++ps) {
        float od = __shfl_xor(bd[ps], 16); int oi = __shfl_xor(bi[ps], 16);
        if (od < bd[ps] || (od == bd[ps] && oi < bi[ps])) { bd[ps] = od; bi[ps] = oi; }
        od = __shfl_xor(bd[ps], 32); oi = __shfl_xor(bi[ps], 32);
        if (od < bd[ps] || (od == bd[ps] && oi < bi[ps])) { bd[ps] = od; bi[ps] = oi; }
    }

    if (valid && grp == 0) {
#pragma unroll
        for (int ps = 0; ps < 4; ++ps) {
            int p = jc * 64 + ps * 16 + l15;
            if (p < N_POINTS) {
                out_idx[p]  = (float)bi[ps];
                out_dist[p] = sqrtf(fmaxf(bd[ps] + x2[ps], 0.f));
            }
        }
    }
}

extern "C" void kernel_launch(void* const* d_in, const int* in_sizes, int n_in,
                              void* d_out, int out_size, void* d_ws, size_t ws_size,
                              hipStream_t stream) {
    const float* X  = (const float*)d_in[0];
    const float* cb = (const float*)d_in[1];
    float* out      = (float*)d_out;

    // workspace: fragment-ordered codebook 128KB | c2 2KB
    _Float16* cbf = (_Float16*)d_ws;
    float*    c2  = (float*)(cbf + (size_t)K_CENT * W_DIM * 2);

    hipLaunchKernelGGL(cvt_kernel, dim3((K_CENT * 8 + 255) / 256), dim3(256), 0, stream, cb, cbf);
    hipLaunchKernelGGL(c2_kernel, dim3((K_CENT + 255) / 256), dim3(256), 0, stream, cb, c2);

    hipLaunchKernelGGL(kmeans_mfma, dim3((N_JOBS + 3) / 4), dim3(256), 0, stream,
                       X, cbf, c2, out, out + N_POINTS);
}

// Round 20
// 100.455 us; speedup vs baseline: 1.0480x; 1.0480x over previous
//
#include <hip/hip_runtime.h>

#define N_POINTS 500000
#define K_CENT   512
#define W_DIM    64
#define N_JOBS   (N_POINTS / 32)   // 15625 exact: 32 points per wave-job

typedef _Float16 half8 __attribute__((ext_vector_type(8)));
typedef float    f32x4 __attribute__((ext_vector_type(4)));

// ---- pre-kernel 1: codebook -> 16x16x32-fragment-ordered f16 hi/lo of w=-2c.
// Layout: [t:16][plane:2][csub:2][kstep:2][lane:64][j:8] -> 8 KB/chunk,
// chunks contiguous (LDS DMA of PAIRS). cent c = t*32 + csub*16 + (l&15),
// dim d = kstep*32 + (l>>4)*8 + j. lo = unscaled residual. (Verified R11-R16;
// R19 proved the lo plane is REQUIRED: single-pass f16 flips argmin.)
__global__ void cvt_kernel(const float* __restrict__ cb,
                           _Float16* __restrict__ cbf) {
    int id = blockIdx.x * 256 + threadIdx.x;           // 4096 ids
    if (id >= K_CENT * 8) return;
    int c = id >> 3, o = (id & 7) * 8;                 // centroid, dim base
    int t = c >> 5, csub = (c >> 4) & 1, r = c & 15;
    int kstep = o >> 5, grp = (o >> 3) & 3;
    int lane = grp * 16 + r;
    const float* src = cb + (size_t)c * W_DIM + o;
    half8 h, l;
#pragma unroll
    for (int j = 0; j < 8; ++j) {
        float w = -2.0f * src[j];
        _Float16 hh = (_Float16)w;                     // RNE
        h[j] = hh;
        l[j] = (_Float16)(w - (float)hh);              // unscaled residual
    }
    size_t bh = ((((size_t)t * 2 + 0) * 2 + csub) * 2 + kstep) * 512 + (size_t)lane * 8;
    size_t bl = ((((size_t)t * 2 + 1) * 2 + csub) * 2 + kstep) * 512 + (size_t)lane * 8;
    *(half8*)(cbf + bh) = h;
    *(half8*)(cbf + bl) = l;
}

// ---- pre-kernel 2: c2[c] = ||c||^2 in double (deterministic, exact bias)
__global__ void c2_kernel(const float* __restrict__ cb, float* __restrict__ c2) {
    int c = blockIdx.x * 256 + threadIdx.x;
    if (c >= K_CENT) return;
    const float4* row = (const float4*)(cb + (size_t)c * W_DIM);
    double s = 0.0;
#pragma unroll
    for (int j = 0; j < W_DIM / 4; ++j) {
        float4 v = row[j];
        s += (double)v.x * v.x + (double)v.y * v.y + (double)v.z * v.z + (double)v.w * v.w;
    }
    c2[c] = (float)s;
}

#define MFMA16(A, B, C) __builtin_amdgcn_mfma_f32_16x16x32_f16(A, B, C, 0, 0, 0)

// Stage chunk PAIR (T, T+1) = 16 KB into abuf[BUF]; per wave 4 KB = 4 calls.
// LDS dest linear (wave-uniform base + lane*16); global src per-lane.
#define STAGE_PAIR(T, BUF)                                                     \
    {                                                                          \
        const __attribute__((address_space(1))) _Float16* g =                  \
            (const __attribute__((address_space(1))) _Float16*)                \
            (cbf + (size_t)(T) * 4096 + (size_t)wave * 2048 + (size_t)lane * 8); \
        __builtin_amdgcn_global_load_lds(                                      \
            (const __attribute__((address_space(1))) void*)g,                  \
            (__attribute__((address_space(3))) void*)&abuf[BUF][wave * 2048], 16, 0, 0); \
        __builtin_amdgcn_global_load_lds(                                      \
            (const __attribute__((address_space(1))) void*)(g + 512),          \
            (__attribute__((address_space(3))) void*)&abuf[BUF][wave * 2048 + 512], 16, 0, 0); \
        __builtin_amdgcn_global_load_lds(                                      \
            (const __attribute__((address_space(1))) void*)(g + 1024),         \
            (__attribute__((address_space(3))) void*)&abuf[BUF][wave * 2048 + 1024], 16, 0, 0); \
        __builtin_amdgcn_global_load_lds(                                      \
            (const __attribute__((address_space(1))) void*)(g + 1536),         \
            (__attribute__((address_space(3))) void*)&abuf[BUF][wave * 2048 + 1536], 16, 0, 0); \
    }

// 24 MFMAs for one chunk at half-buffer offset OFF within abuf[BUF]:
// 4 chains (cs,ps) x 6-deep 3-term (hi*hi ks0/ks1, lo_w*hi ks0/ks1,
// hi_w*lo ks0/ks1), C-in = Q0/Q1 (c2). Static offsets -> immediate LDS addrs.
#define MFMA_PHASE(BUF, OFF, ACC, Q0, Q1)                                      \
    {                                                                          \
        half8 aH[2][2], aL[2][2];                                              \
        _Pragma("unroll")                                                      \
        for (int cs = 0; cs < 2; ++cs)                                         \
            _Pragma("unroll")                                                  \
            for (int ks = 0; ks < 2; ++ks) {                                   \
                aH[cs][ks] = *(const half8*)&abuf[BUF][(OFF) + (cs * 2 + ks) * 512 + lane * 8]; \
                aL[cs][ks] = *(const half8*)&abuf[BUF][(OFF) + 2048 + (cs * 2 + ks) * 512 + lane * 8]; \
            }                                                                  \
        __builtin_amdgcn_s_setprio(1);                                         \
        _Pragma("unroll")                                                      \
        for (int cs = 0; cs < 2; ++cs)                                         \
            _Pragma("unroll")                                                  \
            for (int ps = 0; ps < 2; ++ps)                                     \
                ACC[cs][ps] = MFMA16(aH[cs][0], bh[ps][0], cs ? Q1 : Q0);      \
        _Pragma("unroll")                                                      \
        for (int cs = 0; cs < 2; ++cs)                                         \
            _Pragma("unroll")                                                  \
            for (int ps = 0; ps < 2; ++ps)                                     \
                ACC[cs][ps] = MFMA16(aH[cs][1], bh[ps][1], ACC[cs][ps]);       \
        _Pragma("unroll")                                                      \
        for (int cs = 0; cs < 2; ++cs)                                         \
            _Pragma("unroll")                                                  \
            for (int ps = 0; ps < 2; ++ps)                                     \
                ACC[cs][ps] = MFMA16(aL[cs][0], bh[ps][0], ACC[cs][ps]);       \
        _Pragma("unroll")                                                      \
        for (int cs = 0; cs < 2; ++cs)                                         \
            _Pragma("unroll")                                                  \
            for (int ps = 0; ps < 2; ++ps)                                     \
                ACC[cs][ps] = MFMA16(aL[cs][1], bh[ps][1], ACC[cs][ps]);       \
        _Pragma("unroll")                                                      \
        for (int cs = 0; cs < 2; ++cs)                                         \
            _Pragma("unroll")                                                  \
            for (int ps = 0; ps < 2; ++ps)                                     \
                ACC[cs][ps] = MFMA16(aH[cs][0], bl[ps][0], ACC[cs][ps]);       \
        _Pragma("unroll")                                                      \
        for (int cs = 0; cs < 2; ++cs)                                         \
            _Pragma("unroll")                                                  \
            for (int ps = 0; ps < 2; ++ps)                                     \
                ACC[cs][ps] = MFMA16(aH[cs][1], bl[ps][1], ACC[cs][ps]);       \
        __builtin_amdgcn_s_setprio(0);                                         \
    }

// 16-value argmin per chunk-PAIR (TA, TA+1): v0..7 = accP, v8..15 = accQ.
// Tree (prefer-left) + binary descent; order-independent via explicit
// (m==bd && ci<bi) tie-break; ci monotone in ji within the pair.
#define PAIR_ARGMIN(TA)                                                        \
    {                                                                          \
        _Pragma("unroll")                                                      \
        for (int ps = 0; ps < 2; ++ps) {                                       \
            float v0 = accP[0][ps][0], v1 = accP[0][ps][1];                    \
            float v2 = accP[0][ps][2], v3 = accP[0][ps][3];                    \
            float v4 = accP[1][ps][0], v5 = accP[1][ps][1];                    \
            float v6 = accP[1][ps][2], v7 = accP[1][ps][3];                    \
            float v8 = accQ[0][ps][0], v9 = accQ[0][ps][1];                    \
            float v10 = accQ[0][ps][2], v11 = accQ[0][ps][3];                  \
            float v12 = accQ[1][ps][0], v13 = accQ[1][ps][1];                  \
            float v14 = accQ[1][ps][2], v15 = accQ[1][ps][3];                  \
            float a0 = fminf(v0, v1),   a1 = fminf(v2, v3);                    \
            float a2 = fminf(v4, v5),   a3 = fminf(v6, v7);                    \
            float a4 = fminf(v8, v9),   a5 = fminf(v10, v11);                  \
            float a6 = fminf(v12, v13), a7 = fminf(v14, v15);                  \
            float b0 = fminf(a0, a1), b1 = fminf(a2, a3);                      \
            float b2 = fminf(a4, a5), b3 = fminf(a6, a7);                      \
            float c0 = fminf(b0, b1), c1 = fminf(b2, b3);                      \
            float m  = fminf(c0, c1);                                          \
            bool  L3 = (m == c0);                                              \
            float bL = L3 ? b0 : b2;                                           \
            bool  L2 = (m == bL);                                              \
            float aL = L3 ? (L2 ? a0 : a2) : (L2 ? a4 : a6);                   \
            bool  L1 = (m == aL);                                              \
            float vE = L3 ? (L2 ? (L1 ? v0 : v2) : (L1 ? v4 : v6))             \
                          : (L2 ? (L1 ? v8 : v10) : (L1 ? v12 : v14));         \
            bool  L0 = (m == vE);                                              \
            int ji = (L3 ? 0 : 8) | (L2 ? 0 : 4) | (L1 ? 0 : 2) | (L0 ? 0 : 1); \
            int jj = ji & 7;                                                   \
            int ci = ((TA) + (ji >> 3)) * 32 + (jj >> 2) * 16 + grp4 + (jj & 3); \
            bool imp = (m < bd[ps]) || (m == bd[ps] && ci < bi[ps]);           \
            bd[ps] = imp ? m : bd[ps];                                         \
            bi[ps] = imp ? ci : bi[ps];                                        \
        }                                                                      \
    }

// ---- main kernel: R16 structure with PAIR staging -> ONE barrier per
// chunk-pair (8/sweep vs 16). 4 waves/block, 32 points/wave, rotation.
__global__ __launch_bounds__(256, 2)
void kmeans_mfma(const float* __restrict__ X,
                 const _Float16* __restrict__ cbf,
                 const float* __restrict__ c2,
                 float* __restrict__ out_idx,
                 float* __restrict__ out_dist) {
    __shared__ _Float16 abuf[2][8192];     // 2 x 16 KB pair double buffer
    __shared__ float c2s[K_CENT];          // 2 KB   (total 34 KB -> 4 blk/CU)
    int tid = threadIdx.x;
    c2s[tid] = c2[tid];
    c2s[tid + 256] = c2[tid + 256];

    int wave = tid >> 6;
    int lane = tid & 63;
    int l15  = lane & 15;
    int grp  = lane >> 4;        // 0..3
    int grp4 = grp * 4;
    int grp8 = grp * 8;
    int rot  = (blockIdx.x & 7) * 2;   // even rotation: pairs never wrap

    int job   = blockIdx.x * 4 + wave;
    int valid = job < N_JOBS;
    int jc    = valid ? job : (N_JOBS - 1);   // invalid waves still hit barriers

    // ---- load + convert X: 2 point-subtiles x 2 K-steps, f16 hi + lo
    half8 bh[2][2], bl[2][2];
    float x2[2] = {0.f, 0.f};
#pragma unroll
    for (int ps = 0; ps < 2; ++ps) {
        int p = jc * 32 + ps * 16 + l15;
#pragma unroll
        for (int ks = 0; ks < 2; ++ks) {
            const float4* xp = (const float4*)(X + (size_t)p * W_DIM + ks * 32 + grp8);
            float4 f0 = xp[0], f1 = xp[1];
            float fa[8] = {f0.x, f0.y, f0.z, f0.w, f1.x, f1.y, f1.z, f1.w};
#pragma unroll
            for (int j = 0; j < 8; ++j) {
                _Float16 hh = (_Float16)fa[j];
                bh[ps][ks][j] = hh;
                bl[ps][ks][j] = (_Float16)(fa[j] - (float)hh);
                x2[ps] = fmaf(fa[j], fa[j], x2[ps]);
            }
        }
    }
#pragma unroll
    for (int ps = 0; ps < 2; ++ps) {    // full ||x||^2 across the 4 row-groups
        x2[ps] += __shfl_xor(x2[ps], 16);
        x2[ps] += __shfl_xor(x2[ps], 32);
    }

    float bd[2] = {3.4e38f, 3.4e38f};
    int   bi[2] = {0, 0};
    f32x4 accP[2][2], accQ[2][2];

    STAGE_PAIR(rot, 0)
    __syncthreads();    // drains vmcnt -> abuf[0] pair + c2s ready

#pragma unroll 1
    for (int it = 0; it < 8; ++it) {
        int ta = (rot + 2 * it) & 15;   // even; pair (ta, ta+1), no wrap
        int b  = it & 1;
        // stage NEXT pair into the other buffer (async, in flight during MFMAs)
        if (it < 7) {
            int tn = (ta + 2) & 15;
            STAGE_PAIR(tn, b ^ 1)
        }
        f32x4 qa0 = *(const f32x4*)&c2s[ta * 32 + grp4];
        f32x4 qa1 = *(const f32x4*)&c2s[ta * 32 + 16 + grp4];
        f32x4 qb0 = *(const f32x4*)&c2s[ta * 32 + 32 + grp4];
        f32x4 qb1 = *(const f32x4*)&c2s[ta * 32 + 48 + grp4];
        MFMA_PHASE(b, 0,    accP, qa0, qa1)      // chunk ta
        MFMA_PHASE(b, 4096, accQ, qb0, qb1)      // chunk ta+1
        PAIR_ARGMIN(ta)
        __syncthreads();   // next pair staged everywhere; this buffer free
    }

    // cross-lane combine over the 4 row-groups (disjoint cents per group);
    // explicit lower-index preference on fp-equal ties.
#pragma unroll
    for (int ps = 0; ps < 2; ++ps) {
        float od = __shfl_xor(bd[ps], 16); int oi = __shfl_xor(bi[ps], 16);
        if (od < bd[ps] || (od == bd[ps] && oi < bi[ps])) { bd[ps] = od; bi[ps] = oi; }
        od = __shfl_xor(bd[ps], 32); oi = __shfl_xor(bi[ps], 32);
        if (od < bd[ps] || (od == bd[ps] && oi < bi[ps])) { bd[ps] = od; bi[ps] = oi; }
    }

    if (valid && grp == 0) {
#pragma unroll
        for (int ps = 0; ps < 2; ++ps) {
            int p = jc * 32 + ps * 16 + l15;
            out_idx[p]  = (float)bi[ps];
            out_dist[p] = sqrtf(fmaxf(bd[ps] + x2[ps], 0.f));
        }
    }
}

extern "C" void kernel_launch(void* const* d_in, const int* in_sizes, int n_in,
                              void* d_out, int out_size, void* d_ws, size_t ws_size,
                              hipStream_t stream) {
    const float* X  = (const float*)d_in[0];
    const float* cb = (const float*)d_in[1];
    float* out      = (float*)d_out;

    // workspace: fragment-ordered codebook 128KB | c2 2KB
    _Float16* cbf = (_Float16*)d_ws;
    float*    c2  = (float*)(cbf + (size_t)K_CENT * W_DIM * 2);

    hipLaunchKernelGGL(cvt_kernel, dim3((K_CENT * 8 + 255) / 256), dim3(256), 0, stream, cb, cbf);
    hipLaunchKernelGGL(c2_kernel, dim3((K_CENT + 255) / 256), dim3(256), 0, stream, cb, c2);

    hipLaunchKernelGGL(kmeans_mfma, dim3((N_JOBS + 3) / 4), dim3(256), 0, stream,
                       X, cbf, c2, out, out + N_POINTS);
}